// Round 5
// baseline (282.286 us; speedup 1.0000x reference)
//
#include <hip/hip_runtime.h>
#include <hip/hip_bf16.h>
#include <type_traits>

typedef __bf16 bf16;
typedef __bf16 bf16x2 __attribute__((ext_vector_type(2)));
typedef __bf16 bf16x4 __attribute__((ext_vector_type(4)));
typedef __bf16 bf16x8 __attribute__((ext_vector_type(8)));
typedef float f32x4 __attribute__((ext_vector_type(4)));

#define AS1 __attribute__((address_space(1)))
#define AS3 __attribute__((address_space(3)))

// 0.125 (1/sqrt(64)) * log2(e): folded into Q so attn scores are log2-domain.
#define KAPPA 0.180336880111f

__device__ __forceinline__ void load_lds16(const void* g, void* l) {
  __builtin_amdgcn_global_load_lds((AS1 void*)g, (AS3 void*)l, 16, 0, 0);
}
__device__ __forceinline__ float exp2_fast(float x) {
  return __builtin_amdgcn_exp2f(x);
}

// ---------------------------------------------------------------------------
// All fp32->bf16 conversions in one launch.
// ---------------------------------------------------------------------------
__global__ void f2b_all(const float* __restrict__ x, const float* __restrict__ wq,
                        const float* __restrict__ wk, const float* __restrict__ wv,
                        const float* __restrict__ wo, bf16* __restrict__ xb,
                        bf16* __restrict__ wqkv, bf16* __restrict__ wob) {
  int bid = blockIdx.x;
  const float* src;
  bf16* dst;
  int off;
  if (bid < 8192) { src = x; dst = xb; off = bid; }
  else if (bid < 12288) { src = wq; dst = wqkv; off = bid - 8192; }
  else if (bid < 13312) { src = wk; dst = wqkv + 4194304; off = bid - 12288; }
  else if (bid < 14336) { src = wv; dst = wqkv + 5242880; off = bid - 13312; }
  else { src = wo; dst = wob; off = bid - 14336; }
  int i = (off * 256 + threadIdx.x) * 4;
  float4 v = *(const float4*)(src + i);
  bf16x4 o = {(bf16)v.x, (bf16)v.y, (bf16)v.z, (bf16)v.w};
  *(bf16x4*)(dst + i) = o;
}

// ---------------------------------------------------------------------------
// Fused QKV projection GEMM. Diagnosis after 5 schedule variants all landed
// 560-630 TF / MfmaUtil 21-25% / no pipe saturated: latency-bound from
// insufficient TLP (pipelined variants ran 1 block/CU -> 2 waves/SIMD in
// barrier lockstep; nothing runs during drains). This round combines the
// counted-vmcnt pipeline with CROSS-BLOCK wave diversity (m114 mechanism):
//   128x128 tile, 4 waves (256 thr), BK=32, 3-slot LDS ring (48 KB)
//   -> 3 blocks/CU (144 KB LDS, 12 waves/CU), grid 24x32 = 768 = exactly 3/CU.
//   Per K-tile: stage(tk+2) -> 8 ds_read_b128 -> lgkm(0) -> 16 MFMA ->
//   counted vmcnt(4) (tile tk+1 landed; tk+2 in flight; 0 only at tail) ->
//   ONE s_barrier. Independent blocks on the same CU fill each other's
//   barrier/latency gaps.
// LDS rows 64B (4 x 16B segs), seg ^= (ro>>1)&3 on the GLOBAL source
//   (linear LDS dest, both-sides-or-neither): 8-lane ds_read_b128 group hits
//   slots 4*(row&1)+(qd^((row>>1)&3)) = bijection 0..7 -> conflict-free
//   (VERIFIED: 0 in rocprof rounds 2-4). Read-side seg offset is the
//   per-thread constant (qd ^ ((ln>>1)&3))*16.
// Hazard ledger: stage(tk+2) overwrites slot (tk-1)%3, whose reads drained
//   (lgkm(0)) before iter tk-1's barrier. vmcnt(4) retires tile tk+1's 4
//   loads; tail: tk==62 -> vmcnt(0), tk==63 -> none.
// Epilogue (round-0 harness-verified): bn<16 -> Q+rope*KAPPA (B,32,S,64);
//   bn 16-19 -> K+rope (B,8,S,64); bn 20-23 -> V^T (B,8,64,S). Each wave
//   owns a full 64-col head (wn = (wave&1)*64).
// ---------------------------------------------------------------------------
__global__ __launch_bounds__(256, 3) void gemm_qkv(const bf16* __restrict__ A,
                                                   const bf16* __restrict__ Bw,
                                                   const float* __restrict__ fc,
                                                   const float* __restrict__ fs,
                                                   bf16* __restrict__ Qro,
                                                   bf16* __restrict__ Kro,
                                                   bf16* __restrict__ Vt) {
  const int K = 2048;
  __shared__ bf16 As[3][128][32];  // 24 KB ring (3 slots x 8 KB)
  __shared__ bf16 Bs[3][128][32];  // 24 KB ring
  const int t = threadIdx.x;
  const int wave = t >> 6, lane = t & 63, qd = lane >> 4, ln = lane & 15;
  const int wm = (wave >> 1) * 64;
  const int wn = (wave & 1) * 64;
  const int bn = blockIdx.x;  // 0..23 (Q:0-15, K:16-19, V:20-23)
  const size_t bm = (size_t)blockIdx.y * 128;

  const bf16* Ab = A + bm * (size_t)K;
  const bf16* Bb = Bw + (size_t)bn * 128 * K;

  // Stage one 128x32 tile (8 KB) into ring slot: 2 subs x 256 thr x 16 B.
  auto stage = [&](const bf16* gb, char* lb, int tk, int slot) {
#pragma unroll
    for (int sub = 0; sub < 2; sub++) {
      int e = sub * 256 + t;
      int ro = e >> 2, gs = (e & 3) ^ ((ro >> 1) & 3);
      load_lds16(gb + (size_t)ro * K + tk * 32 + gs * 8,
                 lb + slot * 8192 + sub * 4096 + wave * 1024);
    }
  };

  // Prologue: stage tiles 0,1 (8 loads/wave); land tile 0, keep tile 1 going.
  stage(Ab, (char*)As, 0, 0);
  stage(Bb, (char*)Bs, 0, 0);
  stage(Ab, (char*)As, 1, 1);
  stage(Bb, (char*)Bs, 1, 1);
  asm volatile("s_waitcnt vmcnt(4)" ::: "memory");
  __builtin_amdgcn_s_barrier();

  f32x4 acc[4][4] = {};
  // (row>>1)&3 == (ln>>1)&3 for every fragment row (bases are 16-multiples).
  const int segoff = (qd ^ ((ln >> 1) & 3)) << 4;

  int cs = 0, ps = 2;  // current slot, prefetch slot
  for (int tk = 0; tk < 64; tk++) {
    if (tk < 62) {  // stage tile tk+2 into slot (tk+2)%3 == (tk-1)%3
      stage(Ab, (char*)As, tk + 2, ps);
      stage(Bb, (char*)Bs, tk + 2, ps);
    }
    const char* Asl = (const char*)As + cs * 8192;
    const char* Bsl = (const char*)Bs + cs * 8192;

    bf16x8 af[4], bfr[4];
#pragma unroll
    for (int i = 0; i < 4; i++)
      af[i] = *(const bf16x8*)(Asl + (wm + i * 16 + ln) * 64 + segoff);
#pragma unroll
    for (int j = 0; j < 4; j++)
      bfr[j] = *(const bf16x8*)(Bsl + (wn + j * 16 + ln) * 64 + segoff);

    asm volatile("s_waitcnt lgkmcnt(0)" ::: "memory");
    __builtin_amdgcn_sched_barrier(0);
    __builtin_amdgcn_s_setprio(1);
#pragma unroll
    for (int i = 0; i < 4; i++)
#pragma unroll
      for (int j = 0; j < 4; j++)
        acc[i][j] = __builtin_amdgcn_mfma_f32_16x16x32_bf16(af[i], bfr[j],
                                                            acc[i][j], 0, 0, 0);
    __builtin_amdgcn_s_setprio(0);

    // Counted wait: tile tk+1 must land before next iter's reads.
    if (tk < 62) asm volatile("s_waitcnt vmcnt(4)" ::: "memory");
    else if (tk == 62) asm volatile("s_waitcnt vmcnt(0)" ::: "memory");
    __builtin_amdgcn_s_barrier();
    cs = (cs == 2) ? 0 : cs + 1;
    ps = (ps == 2) ? 0 : ps + 1;
  }

  // ---- epilogue (round-0 verified) ----
  const int b = (int)(bm >> 11);
  const int sb = (int)(bm & 2047) + wm;
  const bool odd = ln & 1;

  if (bn < 20) {  // Q or K: rope, head-major output
    const bool isQ = bn < 16;
    const float kap = isQ ? KAPPA : 1.0f;
    const int hh = isQ ? (bn * 2 + (wn >> 6)) : ((bn - 16) * 2 + (wn >> 6));
    bf16* dst = isQ ? (Qro + ((size_t)(b * 32 + hh) * 2048) * 64)
                    : (Kro + ((size_t)(b * 8 + hh) * 2048) * 64);
#pragma unroll
    for (int i = 0; i < 4; i++) {
#pragma unroll
      for (int j = 0; j < 4; j++) {
        const int d = j * 16 + ln;
        const int i_f = d >> 1;
#pragma unroll
        for (int r = 0; r < 4; r++) {
          int s = sb + i * 16 + qd * 4 + r;
          float v = acc[i][j][r];
          float p = __shfl_xor(v, 1);
          float cv = fc[s * 32 + i_f] * kap;
          float sv = fs[s * 32 + i_f] * kap;
          float o = odd ? (p * sv + v * cv) : (v * cv - p * sv);
          dst[(size_t)s * 64 + d] = (bf16)o;
        }
      }
    }
  } else {  // V: write transposed (B,8,64,S)
    const int kh = (bn - 20) * 2 + (wn >> 6);
#pragma unroll
    for (int i = 0; i < 4; i++)
#pragma unroll
      for (int j = 0; j < 4; j++) {
        const int d = j * 16 + ln;
        int s = sb + i * 16 + qd * 4;
        bf16x4 ov = {(bf16)acc[i][j][0], (bf16)acc[i][j][1],
                     (bf16)acc[i][j][2], (bf16)acc[i][j][3]};
        *(bf16x4*)&Vt[((size_t)(b * 8 + kh) * 64 + d) * 2048 + s] = ov;
      }
  }
}

// ---------------------------------------------------------------------------
// Output projection GEMM, same pipelined 128x128 / 3-slot-ring structure.
// Grid (2048/128=16, 4096/128=32) = 512 blocks = 2 blocks/CU (8 waves/CU).
// ---------------------------------------------------------------------------
__global__ __launch_bounds__(256, 2) void gemm_bt(const bf16* __restrict__ A,
                                                  const bf16* __restrict__ Bw,
                                                  float* __restrict__ C) {
  const int K = 2048, N = 2048;
  __shared__ bf16 As[3][128][32];
  __shared__ bf16 Bs[3][128][32];
  const int t = threadIdx.x;
  const int wave = t >> 6, lane = t & 63, qd = lane >> 4, ln = lane & 15;
  const int wm = (wave >> 1) * 64;
  const int wn = (wave & 1) * 64;
  const size_t bm = (size_t)blockIdx.y * 128;
  const size_t bn = (size_t)blockIdx.x * 128;

  const bf16* Ab = A + bm * (size_t)K;
  const bf16* Bb = Bw + bn * (size_t)K;

  auto stage = [&](const bf16* gb, char* lb, int tk, int slot) {
#pragma unroll
    for (int sub = 0; sub < 2; sub++) {
      int e = sub * 256 + t;
      int ro = e >> 2, gs = (e & 3) ^ ((ro >> 1) & 3);
      load_lds16(gb + (size_t)ro * K + tk * 32 + gs * 8,
                 lb + slot * 8192 + sub * 4096 + wave * 1024);
    }
  };

  stage(Ab, (char*)As, 0, 0);
  stage(Bb, (char*)Bs, 0, 0);
  stage(Ab, (char*)As, 1, 1);
  stage(Bb, (char*)Bs, 1, 1);
  asm volatile("s_waitcnt vmcnt(4)" ::: "memory");
  __builtin_amdgcn_s_barrier();

  f32x4 acc[4][4] = {};
  const int segoff = (qd ^ ((ln >> 1) & 3)) << 4;

  int cs = 0, ps = 2;
  for (int tk = 0; tk < 64; tk++) {
    if (tk < 62) {
      stage(Ab, (char*)As, tk + 2, ps);
      stage(Bb, (char*)Bs, tk + 2, ps);
    }
    const char* Asl = (const char*)As + cs * 8192;
    const char* Bsl = (const char*)Bs + cs * 8192;

    bf16x8 af[4], bfr[4];
#pragma unroll
    for (int i = 0; i < 4; i++)
      af[i] = *(const bf16x8*)(Asl + (wm + i * 16 + ln) * 64 + segoff);
#pragma unroll
    for (int j = 0; j < 4; j++)
      bfr[j] = *(const bf16x8*)(Bsl + (wn + j * 16 + ln) * 64 + segoff);

    asm volatile("s_waitcnt lgkmcnt(0)" ::: "memory");
    __builtin_amdgcn_sched_barrier(0);
    __builtin_amdgcn_s_setprio(1);
#pragma unroll
    for (int i = 0; i < 4; i++)
#pragma unroll
      for (int j = 0; j < 4; j++)
        acc[i][j] = __builtin_amdgcn_mfma_f32_16x16x32_bf16(af[i], bfr[j],
                                                            acc[i][j], 0, 0, 0);
    __builtin_amdgcn_s_setprio(0);

    if (tk < 62) asm volatile("s_waitcnt vmcnt(4)" ::: "memory");
    else if (tk == 62) asm volatile("s_waitcnt vmcnt(0)" ::: "memory");
    __builtin_amdgcn_s_barrier();
    cs = (cs == 2) ? 0 : cs + 1;
    ps = (ps == 2) ? 0 : ps + 1;
  }

#pragma unroll
  for (int i = 0; i < 4; i++)
#pragma unroll
    for (int j = 0; j < 4; j++)
#pragma unroll
      for (int r = 0; r < 4; r++) {
        size_t row = bm + wm + i * 16 + qd * 4 + r;
        size_t col = bn + wn + j * 16 + ln;
        C[row * N + col] = acc[i][j][r];
      }
}

// ---------------------------------------------------------------------------
// Flash attention, S^T formulation, causal, log2-domain FIXED-POINT softmax:
// p = 2^(s-16). Q fragments in registers; K/V 2-slot ring staged at top of
// iteration (latency hidden under QK^T+softmax+PV); one __syncthreads per
// tile (vmcnt+lgkm drain == exactly the ring hazard requirement).
// Q:(B,32,S,64)  K:(B,8,S,64)  Vt:(B,8,64,S)  ->  O:(B,S,32,64)
// ---------------------------------------------------------------------------
__global__ __launch_bounds__(256, 3) void attn_fwd(const bf16* __restrict__ Q,
                                                   const bf16* __restrict__ Kg,
                                                   const bf16* __restrict__ Vg,
                                                   bf16* __restrict__ O) {
  __shared__ bf16 Ks[2][64][64];  // 16 KB ring
  __shared__ bf16 Vs[2][64][64];  // 16 KB ring, [d][k]
  __shared__ bf16 Ps[128][64];    // [q][k], swizzled
  const int t = threadIdx.x;
  const int wave = t >> 6, lane = t & 63, qd = lane >> 4, ln = lane & 15;
  const int bid = blockIdx.x;
  const int qt = 15 - (bid >> 6);  // longest blocks dispatch first
  const int bh = bid & 63;
  const int b = bh >> 5, h = bh & 31, kh = h >> 2;
  const bf16* Qb = Q + ((size_t)(b * 32 + h) * 2048 + qt * 128) * 64;  // contiguous
  const bf16* Kb = Kg + (size_t)(b * 8 + kh) * 2048 * 64;              // contiguous
  const bf16* Vb = Vg + (size_t)(b * 8 + kh) * 64 * 2048;              // row stride 2048
  char* PsB = (char*)Ps;

  // Q fragments to registers: B-operand frag for q-row wave*32+mi*16+ln,
  // k-slice (kk*4+qd)*8 .. +7 (contiguous bf16x8 in the (S,64) layout).
  bf16x8 qf[2][2];
#pragma unroll
  for (int kk = 0; kk < 2; kk++)
#pragma unroll
    for (int mi = 0; mi < 2; mi++)
      qf[kk][mi] = *(const bf16x8*)(Qb + (wave * 32 + mi * 16 + ln) * 64 +
                                    (kk * 4 + qd) * 8);

  auto stageKV = [&](int kb, int buf) {
#pragma unroll
    for (int i = 0; i < 2; i++) {
      int e = i * 256 + t;
      int row = e >> 3, sg = (e & 7) ^ (row & 7);
      load_lds16(Kb + (size_t)(kb * 64 + row) * 64 + sg * 8,
                 (char*)Ks + buf * 8192 + i * 4096 + wave * 1024);
      load_lds16(Vb + (size_t)row * 2048 + kb * 64 + sg * 8,
                 (char*)Vs + buf * 8192 + i * 4096 + wave * 1024);
    }
  };

  f32x4 o_acc[4][2] = {};
  float l_st[2] = {0.f, 0.f};
  const int q0 = qt * 128 + wave * 32;
  const int nkb = 2 * qt + 2;

  stageKV(0, 0);
  __syncthreads();  // K0/V0 landed (vmcnt drain)

  for (int kb = 0; kb < nkb; kb++) {
    const int cur = kb & 1;
    // Prefetch next tile into the other slot. Its previous content (tile
    // kb-1) was fully read before the last __syncthreads.
    if (kb + 1 < nkb) stageKV(kb + 1, cur ^ 1);
    const char* Ksl = (const char*)Ks + cur * 8192;
    const char* Vsl = (const char*)Vs + cur * 8192;

    // S^T = K*Q^T
    f32x4 s_acc[4][2] = {};
#pragma unroll
    for (int kk = 0; kk < 2; kk++) {
      bf16x8 ak[4];
#pragma unroll
      for (int j = 0; j < 4; j++) {
        int row = j * 16 + ln;
        int ph = (kk * 4 + qd) ^ (ln & 7);
        ak[j] = *(const bf16x8*)(Ksl + row * 128 + ph * 16);
      }
#pragma unroll
      for (int j = 0; j < 4; j++)
#pragma unroll
        for (int mi = 0; mi < 2; mi++)
          s_acc[j][mi] = __builtin_amdgcn_mfma_f32_16x16x32_bf16(
              ak[j], qf[kk][mi], s_acc[j][mi], 0, 0, 0);
    }

    // fixed-point softmax: p = 2^(s-16); masked -> exact 0
    auto smax = [&](auto maskc) {
      constexpr bool MASK = decltype(maskc)::value;
#pragma unroll
      for (int mi = 0; mi < 2; mi++) {
        const int qv = q0 + mi * 16 + ln;
        const int prow = wave * 32 + mi * 16 + ln;
        float rs = 0.f;
#pragma unroll
        for (int j = 0; j < 4; j++) {
          bf16x4 pk;
#pragma unroll
          for (int r = 0; r < 4; r++) {
            float s = s_acc[j][mi][r];
            if (MASK) {
              int k_glob = kb * 64 + j * 16 + qd * 4 + r;
              if (k_glob > qv) s = -1e5f;
            }
            float pv = exp2_fast(s - 16.f);
            rs += pv;
            pk[r] = (bf16)pv;
          }
          int ps = (j * 2 + (qd >> 1)) ^ (ln & 7);
          *(bf16x4*)(PsB + prow * 128 + ps * 16 + (qd & 1) * 8) = pk;
        }
        l_st[mi] += rs;
      }
    };
    if (kb * 64 + 63 > q0) smax(std::true_type{});
    else smax(std::false_type{});

    // O^T += V^T * P^T  (Ps wave-private; lgkmcnt orders write->read)
#pragma unroll
    for (int kk = 0; kk < 2; kk++) {
      bf16x8 av[4], bp[2];
#pragma unroll
      for (int dj = 0; dj < 4; dj++) {
        int row = dj * 16 + ln;
        int ph = (kk * 4 + qd) ^ (ln & 7);
        av[dj] = *(const bf16x8*)(Vsl + row * 128 + ph * 16);
      }
#pragma unroll
      for (int mi = 0; mi < 2; mi++) {
        int prow = wave * 32 + mi * 16 + ln;
        int ph = (kk * 4 + qd) ^ (ln & 7);
        bp[mi] = *(const bf16x8*)(PsB + prow * 128 + ph * 16);
      }
#pragma unroll
      for (int dj = 0; dj < 4; dj++)
#pragma unroll
        for (int mi = 0; mi < 2; mi++)
          o_acc[dj][mi] = __builtin_amdgcn_mfma_f32_16x16x32_bf16(
              av[dj], bp[mi], o_acc[dj][mi], 0, 0, 0);
    }

    // Drains vmcnt(0) (next tile landed) + lgkm (this tile's reads done):
    // exactly the ring hazard requirements, once per tile.
    __syncthreads();
  }

  // epilogue: reduce l across quads (each quad summed a disjoint k-subset)
#pragma unroll
  for (int mi = 0; mi < 2; mi++) {
    float lt = l_st[mi];
    lt += __shfl_xor(lt, 16);
    lt += __shfl_xor(lt, 32);
    float inv = 1.f / lt;
    int q_idx = qt * 128 + wave * 32 + mi * 16 + ln;
#pragma unroll
    for (int dj = 0; dj < 4; dj++) {
      bf16x4 ov;
#pragma unroll
      for (int r = 0; r < 4; r++) ov[r] = (bf16)(o_acc[dj][mi][r] * inv);
      *(bf16x4*)&O[((size_t)(b * 2048 + q_idx) * 32 + h) * 64 + dj * 16 + qd * 4] = ov;
    }
  }
}

// ---------------------------------------------------------------------------
extern "C" void kernel_launch(void* const* d_in, const int* in_sizes, int n_in,
                              void* d_out, int out_size, void* d_ws,
                              size_t ws_size, hipStream_t stream) {
  const float* x = (const float*)d_in[0];
  const float* fc = (const float*)d_in[1];
  const float* fs = (const float*)d_in[2];
  const float* wq = (const float*)d_in[3];
  const float* wk = (const float*)d_in[4];
  const float* wv = (const float*)d_in[5];
  const float* wo = (const float*)d_in[6];
  float* out = (float*)d_out;

  char* ws = (char*)d_ws;
  const size_t MB = (size_t)1 << 20;
  bf16* xb   = (bf16*)(ws + 0 * MB);   // 16 MB (4096,2048)
  bf16* wqkv = (bf16*)(ws + 16 * MB);  // 12 MB (3072,2048)
  bf16* wob  = (bf16*)(ws + 28 * MB);  // 8 MB
  bf16* Qro  = (bf16*)(ws + 36 * MB);  // 16 MB (B,32,S,64), roped*KAPPA
  bf16* Kro  = (bf16*)(ws + 52 * MB);  // 4 MB  (B,8,S,64), roped
  bf16* Vt   = (bf16*)(ws + 56 * MB);  // 4 MB  (B,8,64,S)
  bf16* Oa   = (bf16*)(ws + 60 * MB);  // 16 MB (B,S,32,64)

  dim3 blk(256);
  f2b_all<<<18432, blk, 0, stream>>>(x, wq, wk, wv, wo, xb, wqkv, wob);
  gemm_qkv<<<dim3(24, 32), blk, 0, stream>>>(xb, wqkv, fc, fs, Qro, Kro, Vt);
  attn_fwd<<<1024, blk, 0, stream>>>(Qro, Kro, Vt, Oa);
  gemm_bt<<<dim3(16, 32), blk, 0, stream>>>(Oa, wob, out);
}

// Round 6
// 275.951 us; speedup vs baseline: 1.0230x; 1.0230x over previous
//
#include <hip/hip_runtime.h>
#include <hip/hip_bf16.h>
#include <type_traits>

typedef __bf16 bf16;
typedef __bf16 bf16x2 __attribute__((ext_vector_type(2)));
typedef __bf16 bf16x4 __attribute__((ext_vector_type(4)));
typedef __bf16 bf16x8 __attribute__((ext_vector_type(8)));
typedef float f32x4 __attribute__((ext_vector_type(4)));

#define AS1 __attribute__((address_space(1)))
#define AS3 __attribute__((address_space(3)))

// 0.125 (1/sqrt(64)) * log2(e): folded into Q so attn scores are log2-domain.
#define KAPPA 0.180336880111f

__device__ __forceinline__ void load_lds16(const void* g, void* l) {
  __builtin_amdgcn_global_load_lds((AS1 void*)g, (AS3 void*)l, 16, 0, 0);
}
__device__ __forceinline__ float exp2_fast(float x) {
  return __builtin_amdgcn_exp2f(x);
}

// ---------------------------------------------------------------------------
// All fp32->bf16 conversions in one launch.
// ---------------------------------------------------------------------------
__global__ void f2b_all(const float* __restrict__ x, const float* __restrict__ wq,
                        const float* __restrict__ wk, const float* __restrict__ wv,
                        const float* __restrict__ wo, bf16* __restrict__ xb,
                        bf16* __restrict__ wqkv, bf16* __restrict__ wob) {
  int bid = blockIdx.x;
  const float* src;
  bf16* dst;
  int off;
  if (bid < 8192) { src = x; dst = xb; off = bid; }
  else if (bid < 12288) { src = wq; dst = wqkv; off = bid - 8192; }
  else if (bid < 13312) { src = wk; dst = wqkv + 4194304; off = bid - 12288; }
  else if (bid < 14336) { src = wv; dst = wqkv + 5242880; off = bid - 13312; }
  else { src = wo; dst = wob; off = bid - 14336; }
  int i = (off * 256 + threadIdx.x) * 4;
  float4 v = *(const float4*)(src + i);
  bf16x4 o = {(bf16)v.x, (bf16)v.y, (bf16)v.z, (bf16)v.w};
  *(bf16x4*)(dst + i) = o;
}

// ---------------------------------------------------------------------------
// Fused QKV projection GEMM. Round-5 (verified): counted-vmcnt pipeline x
// 3 blocks/CU (cross-block TLP) -> 71.9 us / MfmaUtil 30%. This round removes
// the last forced stall: round-5 drained lgkmcnt(0) BEFORE the MFMA cluster
// (full LDS latency on the critical path every phase). Now fragments are
// REGISTER DOUBLE-BUFFERED: iter tk reads tile tk+1's frags while MFMAing
// tile tk from the other set -- MFMA never waits on LDS; lgkm(0) moves after
// the cluster (needed only for the slot-reuse barrier, already drained).
//   128x128 tile, 4 waves, BK=32, 3-slot LDS ring (48 KB) -> 3 blocks/CU,
//   grid 24x32 = 768 = exactly 3/CU. Stage distance 3.
// Ledger: iter tk = { stage tk+3 -> slot tk%3 (tile tk's reads done iter
//   tk-1, lgkm-drained before last barrier); ds_read tk+1 -> nxt set (landed:
//   vmcnt(4) end of iter tk-1 retired its 4 loads); MFMA tk from cur set;
//   lgkm(0); vmcnt(4) retires tk+2 (tk+3 stays in flight); barrier }.
//   Tail: stage stops tk=60; vmcnt(0) at tk=61; reads stop tk=62.
// Frag sets alternate via 2x-unrolled body (static reg indexing).
// LDS rows 64B (4 x 16B segs), seg ^= (ro>>1)&3 on the GLOBAL source
//   (linear LDS dest): slots 4*(row&1)+(qd^((row>>1)&3)) bijective 0..7 ->
//   conflict-free (VERIFIED 0 in rocprof). Read-side seg offset constant.
// Epilogue (round-0 verified): bn<16 -> Q+rope*KAPPA; 16-19 -> K+rope;
//   20-23 -> V^T. VGPR ~145 -> 3 waves/SIMD (512/145=3.5) = 12 waves/CU.
// ---------------------------------------------------------------------------
__global__ __launch_bounds__(256, 3) void gemm_qkv(const bf16* __restrict__ A,
                                                   const bf16* __restrict__ Bw,
                                                   const float* __restrict__ fc,
                                                   const float* __restrict__ fs,
                                                   bf16* __restrict__ Qro,
                                                   bf16* __restrict__ Kro,
                                                   bf16* __restrict__ Vt) {
  const int K = 2048;
  __shared__ bf16 As[3][128][32];  // 24 KB ring (3 slots x 8 KB)
  __shared__ bf16 Bs[3][128][32];  // 24 KB ring
  const int t = threadIdx.x;
  const int wave = t >> 6, lane = t & 63, qd = lane >> 4, ln = lane & 15;
  const int wm = (wave >> 1) * 64;
  const int wn = (wave & 1) * 64;
  const int bn = blockIdx.x;  // 0..23 (Q:0-15, K:16-19, V:20-23)
  const size_t bm = (size_t)blockIdx.y * 128;

  const bf16* Ab = A + bm * (size_t)K;
  const bf16* Bb = Bw + (size_t)bn * 128 * K;

  auto stage = [&](const bf16* gb, char* lb, int tk, int slot) {
#pragma unroll
    for (int sub = 0; sub < 2; sub++) {
      int e = sub * 256 + t;
      int ro = e >> 2, gs = (e & 3) ^ ((ro >> 1) & 3);
      load_lds16(gb + (size_t)ro * K + tk * 32 + gs * 8,
                 lb + slot * 8192 + sub * 4096 + wave * 1024);
    }
  };

  f32x4 acc[4][4] = {};
  const int segoff = (qd ^ ((ln >> 1) & 3)) << 4;
  bf16x8 fa0[4], fb0[4], fa1[4], fb1[4];

  // Prologue: stage 0,1,2; land t0; read t0 -> set0; ensure t1 landed.
  stage(Ab, (char*)As, 0, 0);
  stage(Bb, (char*)Bs, 0, 0);
  stage(Ab, (char*)As, 1, 1);
  stage(Bb, (char*)Bs, 1, 1);
  stage(Ab, (char*)As, 2, 2);
  stage(Bb, (char*)Bs, 2, 2);
  asm volatile("s_waitcnt vmcnt(8)" ::: "memory");
  __builtin_amdgcn_s_barrier();
#pragma unroll
  for (int i = 0; i < 4; i++) {
    fa0[i] = *(const bf16x8*)((const char*)As + (wm + i * 16 + ln) * 64 + segoff);
    fb0[i] = *(const bf16x8*)((const char*)Bs + (wn + i * 16 + ln) * 64 + segoff);
  }
  asm volatile("s_waitcnt lgkmcnt(0) vmcnt(4)" ::: "memory");
  __builtin_amdgcn_sched_barrier(0);
  __builtin_amdgcn_s_barrier();

  // One pipeline step: MFMA tile tk (cur set), read tile tk+1 (nxt set).
  auto step = [&](int tk, bf16x8 (&ca)[4], bf16x8 (&cb)[4],
                  bf16x8 (&na)[4], bf16x8 (&nb)[4]) {
    if (tk < 61) {  // stage tk+3 -> slot tk%3
      stage(Ab, (char*)As, tk + 3, tk % 3);
      stage(Bb, (char*)Bs, tk + 3, tk % 3);
    }
    if (tk < 63) {  // read tk+1 frags -> nxt set (slot (tk+1)%3)
      const char* Asl = (const char*)As + ((tk + 1) % 3) * 8192;
      const char* Bsl = (const char*)Bs + ((tk + 1) % 3) * 8192;
#pragma unroll
      for (int i = 0; i < 4; i++) {
        na[i] = *(const bf16x8*)(Asl + (wm + i * 16 + ln) * 64 + segoff);
        nb[i] = *(const bf16x8*)(Bsl + (wn + i * 16 + ln) * 64 + segoff);
      }
    }
    __builtin_amdgcn_s_setprio(1);
#pragma unroll
    for (int i = 0; i < 4; i++)
#pragma unroll
      for (int j = 0; j < 4; j++)
        acc[i][j] = __builtin_amdgcn_mfma_f32_16x16x32_bf16(ca[i], cb[j],
                                                            acc[i][j], 0, 0, 0);
    __builtin_amdgcn_s_setprio(0);
    if (tk < 63) {
      // lgkm: all waves' reads of slot (tk+1)%3... and this wave's nxt reads
      // done (mostly drained already -- overlapped with MFMA). vmcnt: tile
      // tk+2 landed before next iter reads it.
      if (tk < 61) asm volatile("s_waitcnt lgkmcnt(0) vmcnt(4)" ::: "memory");
      else if (tk == 61) asm volatile("s_waitcnt lgkmcnt(0) vmcnt(0)" ::: "memory");
      else asm volatile("s_waitcnt lgkmcnt(0)" ::: "memory");
      __builtin_amdgcn_sched_barrier(0);
      __builtin_amdgcn_s_barrier();
    }
  };

  for (int tk = 0; tk < 64; tk += 2) {
    step(tk, fa0, fb0, fa1, fb1);
    step(tk + 1, fa1, fb1, fa0, fb0);
  }

  // ---- epilogue (round-0 verified) ----
  const int b = (int)(bm >> 11);
  const int sb = (int)(bm & 2047) + wm;
  const bool odd = ln & 1;

  if (bn < 20) {  // Q or K: rope, head-major output
    const bool isQ = bn < 16;
    const float kap = isQ ? KAPPA : 1.0f;
    const int hh = isQ ? (bn * 2 + (wn >> 6)) : ((bn - 16) * 2 + (wn >> 6));
    bf16* dst = isQ ? (Qro + ((size_t)(b * 32 + hh) * 2048) * 64)
                    : (Kro + ((size_t)(b * 8 + hh) * 2048) * 64);
#pragma unroll
    for (int i = 0; i < 4; i++) {
#pragma unroll
      for (int j = 0; j < 4; j++) {
        const int d = j * 16 + ln;
        const int i_f = d >> 1;
#pragma unroll
        for (int r = 0; r < 4; r++) {
          int s = sb + i * 16 + qd * 4 + r;
          float v = acc[i][j][r];
          float p = __shfl_xor(v, 1);
          float cv = fc[s * 32 + i_f] * kap;
          float sv = fs[s * 32 + i_f] * kap;
          float o = odd ? (p * sv + v * cv) : (v * cv - p * sv);
          dst[(size_t)s * 64 + d] = (bf16)o;
        }
      }
    }
  } else {  // V: write transposed (B,8,64,S)
    const int kh = (bn - 20) * 2 + (wn >> 6);
#pragma unroll
    for (int i = 0; i < 4; i++)
#pragma unroll
      for (int j = 0; j < 4; j++) {
        const int d = j * 16 + ln;
        int s = sb + i * 16 + qd * 4;
        bf16x4 ov = {(bf16)acc[i][j][0], (bf16)acc[i][j][1],
                     (bf16)acc[i][j][2], (bf16)acc[i][j][3]};
        *(bf16x4*)&Vt[((size_t)(b * 8 + kh) * 64 + d) * 2048 + s] = ov;
      }
  }
}

// ---------------------------------------------------------------------------
// Output projection GEMM, same reg-dbuf pipelined 128x128 / 3-slot ring.
// Grid (16,32) = 512 = 2 blocks/CU.
// ---------------------------------------------------------------------------
__global__ __launch_bounds__(256, 2) void gemm_bt(const bf16* __restrict__ A,
                                                  const bf16* __restrict__ Bw,
                                                  float* __restrict__ C) {
  const int K = 2048, N = 2048;
  __shared__ bf16 As[3][128][32];
  __shared__ bf16 Bs[3][128][32];
  const int t = threadIdx.x;
  const int wave = t >> 6, lane = t & 63, qd = lane >> 4, ln = lane & 15;
  const int wm = (wave >> 1) * 64;
  const int wn = (wave & 1) * 64;
  const size_t bm = (size_t)blockIdx.y * 128;
  const size_t bn = (size_t)blockIdx.x * 128;

  const bf16* Ab = A + bm * (size_t)K;
  const bf16* Bb = Bw + bn * (size_t)K;

  auto stage = [&](const bf16* gb, char* lb, int tk, int slot) {
#pragma unroll
    for (int sub = 0; sub < 2; sub++) {
      int e = sub * 256 + t;
      int ro = e >> 2, gs = (e & 3) ^ ((ro >> 1) & 3);
      load_lds16(gb + (size_t)ro * K + tk * 32 + gs * 8,
                 lb + slot * 8192 + sub * 4096 + wave * 1024);
    }
  };

  f32x4 acc[4][4] = {};
  const int segoff = (qd ^ ((ln >> 1) & 3)) << 4;
  bf16x8 fa0[4], fb0[4], fa1[4], fb1[4];

  stage(Ab, (char*)As, 0, 0);
  stage(Bb, (char*)Bs, 0, 0);
  stage(Ab, (char*)As, 1, 1);
  stage(Bb, (char*)Bs, 1, 1);
  stage(Ab, (char*)As, 2, 2);
  stage(Bb, (char*)Bs, 2, 2);
  asm volatile("s_waitcnt vmcnt(8)" ::: "memory");
  __builtin_amdgcn_s_barrier();
#pragma unroll
  for (int i = 0; i < 4; i++) {
    fa0[i] = *(const bf16x8*)((const char*)As + (wm + i * 16 + ln) * 64 + segoff);
    fb0[i] = *(const bf16x8*)((const char*)Bs + (wn + i * 16 + ln) * 64 + segoff);
  }
  asm volatile("s_waitcnt lgkmcnt(0) vmcnt(4)" ::: "memory");
  __builtin_amdgcn_sched_barrier(0);
  __builtin_amdgcn_s_barrier();

  auto step = [&](int tk, bf16x8 (&ca)[4], bf16x8 (&cb)[4],
                  bf16x8 (&na)[4], bf16x8 (&nb)[4]) {
    if (tk < 61) {
      stage(Ab, (char*)As, tk + 3, tk % 3);
      stage(Bb, (char*)Bs, tk + 3, tk % 3);
    }
    if (tk < 63) {
      const char* Asl = (const char*)As + ((tk + 1) % 3) * 8192;
      const char* Bsl = (const char*)Bs + ((tk + 1) % 3) * 8192;
#pragma unroll
      for (int i = 0; i < 4; i++) {
        na[i] = *(const bf16x8*)(Asl + (wm + i * 16 + ln) * 64 + segoff);
        nb[i] = *(const bf16x8*)(Bsl + (wn + i * 16 + ln) * 64 + segoff);
      }
    }
    __builtin_amdgcn_s_setprio(1);
#pragma unroll
    for (int i = 0; i < 4; i++)
#pragma unroll
      for (int j = 0; j < 4; j++)
        acc[i][j] = __builtin_amdgcn_mfma_f32_16x16x32_bf16(ca[i], cb[j],
                                                            acc[i][j], 0, 0, 0);
    __builtin_amdgcn_s_setprio(0);
    if (tk < 63) {
      if (tk < 61) asm volatile("s_waitcnt lgkmcnt(0) vmcnt(4)" ::: "memory");
      else if (tk == 61) asm volatile("s_waitcnt lgkmcnt(0) vmcnt(0)" ::: "memory");
      else asm volatile("s_waitcnt lgkmcnt(0)" ::: "memory");
      __builtin_amdgcn_sched_barrier(0);
      __builtin_amdgcn_s_barrier();
    }
  };

  for (int tk = 0; tk < 64; tk += 2) {
    step(tk, fa0, fb0, fa1, fb1);
    step(tk + 1, fa1, fb1, fa0, fb0);
  }

#pragma unroll
  for (int i = 0; i < 4; i++)
#pragma unroll
    for (int j = 0; j < 4; j++)
#pragma unroll
      for (int r = 0; r < 4; r++) {
        size_t row = bm + wm + i * 16 + qd * 4 + r;
        size_t col = bn + wn + j * 16 + ln;
        C[row * N + col] = acc[i][j][r];
      }
}

// ---------------------------------------------------------------------------
// Flash attention, S^T formulation, causal, log2-domain FIXED-POINT softmax:
// p = 2^(s-16). Q fragments in registers; K/V 2-slot ring staged at top of
// iteration (latency hidden under QK^T+softmax+PV); one __syncthreads per
// tile (vmcnt+lgkm drain == exactly the ring hazard requirement).
// Q:(B,32,S,64)  K:(B,8,S,64)  Vt:(B,8,64,S)  ->  O:(B,S,32,64)
// ---------------------------------------------------------------------------
__global__ __launch_bounds__(256, 3) void attn_fwd(const bf16* __restrict__ Q,
                                                   const bf16* __restrict__ Kg,
                                                   const bf16* __restrict__ Vg,
                                                   bf16* __restrict__ O) {
  __shared__ bf16 Ks[2][64][64];  // 16 KB ring
  __shared__ bf16 Vs[2][64][64];  // 16 KB ring, [d][k]
  __shared__ bf16 Ps[128][64];    // [q][k], swizzled
  const int t = threadIdx.x;
  const int wave = t >> 6, lane = t & 63, qd = lane >> 4, ln = lane & 15;
  const int bid = blockIdx.x;
  const int qt = 15 - (bid >> 6);  // longest blocks dispatch first
  const int bh = bid & 63;
  const int b = bh >> 5, h = bh & 31, kh = h >> 2;
  const bf16* Qb = Q + ((size_t)(b * 32 + h) * 2048 + qt * 128) * 64;  // contiguous
  const bf16* Kb = Kg + (size_t)(b * 8 + kh) * 2048 * 64;              // contiguous
  const bf16* Vb = Vg + (size_t)(b * 8 + kh) * 64 * 2048;              // row stride 2048
  char* PsB = (char*)Ps;

  // Q fragments to registers: B-operand frag for q-row wave*32+mi*16+ln,
  // k-slice (kk*4+qd)*8 .. +7 (contiguous bf16x8 in the (S,64) layout).
  bf16x8 qf[2][2];
#pragma unroll
  for (int kk = 0; kk < 2; kk++)
#pragma unroll
    for (int mi = 0; mi < 2; mi++)
      qf[kk][mi] = *(const bf16x8*)(Qb + (wave * 32 + mi * 16 + ln) * 64 +
                                    (kk * 4 + qd) * 8);

  auto stageKV = [&](int kb, int buf) {
#pragma unroll
    for (int i = 0; i < 2; i++) {
      int e = i * 256 + t;
      int row = e >> 3, sg = (e & 7) ^ (row & 7);
      load_lds16(Kb + (size_t)(kb * 64 + row) * 64 + sg * 8,
                 (char*)Ks + buf * 8192 + i * 4096 + wave * 1024);
      load_lds16(Vb + (size_t)row * 2048 + kb * 64 + sg * 8,
                 (char*)Vs + buf * 8192 + i * 4096 + wave * 1024);
    }
  };

  f32x4 o_acc[4][2] = {};
  float l_st[2] = {0.f, 0.f};
  const int q0 = qt * 128 + wave * 32;
  const int nkb = 2 * qt + 2;

  stageKV(0, 0);
  __syncthreads();  // K0/V0 landed (vmcnt drain)

  for (int kb = 0; kb < nkb; kb++) {
    const int cur = kb & 1;
    // Prefetch next tile into the other slot. Its previous content (tile
    // kb-1) was fully read before the last __syncthreads.
    if (kb + 1 < nkb) stageKV(kb + 1, cur ^ 1);
    const char* Ksl = (const char*)Ks + cur * 8192;
    const char* Vsl = (const char*)Vs + cur * 8192;

    // S^T = K*Q^T
    f32x4 s_acc[4][2] = {};
#pragma unroll
    for (int kk = 0; kk < 2; kk++) {
      bf16x8 ak[4];
#pragma unroll
      for (int j = 0; j < 4; j++) {
        int row = j * 16 + ln;
        int ph = (kk * 4 + qd) ^ (ln & 7);
        ak[j] = *(const bf16x8*)(Ksl + row * 128 + ph * 16);
      }
#pragma unroll
      for (int j = 0; j < 4; j++)
#pragma unroll
        for (int mi = 0; mi < 2; mi++)
          s_acc[j][mi] = __builtin_amdgcn_mfma_f32_16x16x32_bf16(
              ak[j], qf[kk][mi], s_acc[j][mi], 0, 0, 0);
    }

    // fixed-point softmax: p = 2^(s-16); masked -> exact 0
    auto smax = [&](auto maskc) {
      constexpr bool MASK = decltype(maskc)::value;
#pragma unroll
      for (int mi = 0; mi < 2; mi++) {
        const int qv = q0 + mi * 16 + ln;
        const int prow = wave * 32 + mi * 16 + ln;
        float rs = 0.f;
#pragma unroll
        for (int j = 0; j < 4; j++) {
          bf16x4 pk;
#pragma unroll
          for (int r = 0; r < 4; r++) {
            float s = s_acc[j][mi][r];
            if (MASK) {
              int k_glob = kb * 64 + j * 16 + qd * 4 + r;
              if (k_glob > qv) s = -1e5f;
            }
            float pv = exp2_fast(s - 16.f);
            rs += pv;
            pk[r] = (bf16)pv;
          }
          int ps = (j * 2 + (qd >> 1)) ^ (ln & 7);
          *(bf16x4*)(PsB + prow * 128 + ps * 16 + (qd & 1) * 8) = pk;
        }
        l_st[mi] += rs;
      }
    };
    if (kb * 64 + 63 > q0) smax(std::true_type{});
    else smax(std::false_type{});

    // O^T += V^T * P^T  (Ps wave-private; lgkmcnt orders write->read)
#pragma unroll
    for (int kk = 0; kk < 2; kk++) {
      bf16x8 av[4], bp[2];
#pragma unroll
      for (int dj = 0; dj < 4; dj++) {
        int row = dj * 16 + ln;
        int ph = (kk * 4 + qd) ^ (ln & 7);
        av[dj] = *(const bf16x8*)(Vsl + row * 128 + ph * 16);
      }
#pragma unroll
      for (int mi = 0; mi < 2; mi++) {
        int prow = wave * 32 + mi * 16 + ln;
        int ph = (kk * 4 + qd) ^ (ln & 7);
        bp[mi] = *(const bf16x8*)(PsB + prow * 128 + ph * 16);
      }
#pragma unroll
      for (int dj = 0; dj < 4; dj++)
#pragma unroll
        for (int mi = 0; mi < 2; mi++)
          o_acc[dj][mi] = __builtin_amdgcn_mfma_f32_16x16x32_bf16(
              av[dj], bp[mi], o_acc[dj][mi], 0, 0, 0);
    }

    // Drains vmcnt(0) (next tile landed) + lgkm (this tile's reads done):
    // exactly the ring hazard requirements, once per tile.
    __syncthreads();
  }

  // epilogue: reduce l across quads (each quad summed a disjoint k-subset)
#pragma unroll
  for (int mi = 0; mi < 2; mi++) {
    float lt = l_st[mi];
    lt += __shfl_xor(lt, 16);
    lt += __shfl_xor(lt, 32);
    float inv = 1.f / lt;
    int q_idx = qt * 128 + wave * 32 + mi * 16 + ln;
#pragma unroll
    for (int dj = 0; dj < 4; dj++) {
      bf16x4 ov;
#pragma unroll
      for (int r = 0; r < 4; r++) ov[r] = (bf16)(o_acc[dj][mi][r] * inv);
      *(bf16x4*)&O[((size_t)(b * 2048 + q_idx) * 32 + h) * 64 + dj * 16 + qd * 4] = ov;
    }
  }
}

// ---------------------------------------------------------------------------
extern "C" void kernel_launch(void* const* d_in, const int* in_sizes, int n_in,
                              void* d_out, int out_size, void* d_ws,
                              size_t ws_size, hipStream_t stream) {
  const float* x = (const float*)d_in[0];
  const float* fc = (const float*)d_in[1];
  const float* fs = (const float*)d_in[2];
  const float* wq = (const float*)d_in[3];
  const float* wk = (const float*)d_in[4];
  const float* wv = (const float*)d_in[5];
  const float* wo = (const float*)d_in[6];
  float* out = (float*)d_out;

  char* ws = (char*)d_ws;
  const size_t MB = (size_t)1 << 20;
  bf16* xb   = (bf16*)(ws + 0 * MB);   // 16 MB (4096,2048)
  bf16* wqkv = (bf16*)(ws + 16 * MB);  // 12 MB (3072,2048)
  bf16* wob  = (bf16*)(ws + 28 * MB);  // 8 MB
  bf16* Qro  = (bf16*)(ws + 36 * MB);  // 16 MB (B,32,S,64), roped*KAPPA
  bf16* Kro  = (bf16*)(ws + 52 * MB);  // 4 MB  (B,8,S,64), roped
  bf16* Vt   = (bf16*)(ws + 56 * MB);  // 4 MB  (B,8,64,S)
  bf16* Oa   = (bf16*)(ws + 60 * MB);  // 16 MB (B,S,32,64)

  dim3 blk(256);
  f2b_all<<<18432, blk, 0, stream>>>(x, wq, wk, wv, wo, xb, wqkv, wob);
  gemm_qkv<<<dim3(24, 32), blk, 0, stream>>>(xb, wqkv, fc, fs, Qro, Kro, Vt);
  attn_fwd<<<1024, blk, 0, stream>>>(Qro, Kro, Vt, Oa);
  gemm_bt<<<dim3(16, 32), blk, 0, stream>>>(Oa, wob, out);
}